// Round 2
// baseline (470.978 us; speedup 1.0000x reference)
//
#include <hip/hip_runtime.h>
#include <hip/hip_bf16.h>

// B=8, N=256, H=128. Rows M = B*N*N = 524288, flattened r = (b*256+i)*256+j.
// out[r][o] = sum_h e[r][h]*Uw[o][h] + Ub[o] + Vx[b*256+i][o] + Vx[b*256+j][o]
// vx2 = Vx + 0.5*Ub precomputed (d_ws). Main kernel: barrier-free streaming —
// B-fragments (Uw as bf16 MFMA frags) staged in LDS once; each wave owns
// independent 16-row strips; vx terms folded into accumulator init.

using bf16x8 = __attribute__((ext_vector_type(8))) short;
using f32x4  = __attribute__((ext_vector_type(4))) float;

__device__ inline bf16x8 pack8(const float4 a, const float4 b) {
  union { __hip_bfloat162 h2[4]; bf16x8 v; } u;
  u.h2[0] = __float22bfloat162_rn(make_float2(a.x, a.y));
  u.h2[1] = __float22bfloat162_rn(make_float2(a.z, a.w));
  u.h2[2] = __float22bfloat162_rn(make_float2(b.x, b.y));
  u.h2[3] = __float22bfloat162_rn(make_float2(b.z, b.w));
  return u.v;
}

// Kernel 1: vx2[r][o] = sum_h x[r][h]*V_w[o][h] + V_b[o] + 0.5*U_b[o], r in [0,2048)
__global__ __launch_bounds__(256) void vx_kernel(
    const float* __restrict__ x, const float* __restrict__ Vw,
    const float* __restrict__ Vb, const float* __restrict__ Ub,
    float* __restrict__ vx2) {
  __shared__ float xs[8][128];
  const int r0 = blockIdx.x * 8;
  for (int i = threadIdx.x; i < 8 * 32; i += 256)
    ((float4*)&xs[0][0])[i] = ((const float4*)(x + (size_t)r0 * 128))[i];
  __syncthreads();

  const int o    = threadIdx.x & 127;
  const int half = threadIdx.x >> 7;
  float acc[4] = {0.f, 0.f, 0.f, 0.f};
  const float4* vwrow = (const float4*)(Vw + (size_t)o * 128);
#pragma unroll 4
  for (int kc = 0; kc < 32; ++kc) {
    const float4 w4 = vwrow[kc];
#pragma unroll
    for (int r = 0; r < 4; ++r) {
      const float4 xv = ((const float4*)&xs[half * 4 + r][0])[kc];
      acc[r] += xv.x * w4.x + xv.y * w4.y + xv.z * w4.z + xv.w * w4.w;
    }
  }
  const float bias = Vb[o] + 0.5f * Ub[o];
#pragma unroll
  for (int r = 0; r < 4; ++r)
    vx2[(size_t)(r0 + half * 4 + r) * 128 + o] = acc[r] + bias;
}

// Kernel 2: barrier-free streaming GEMM.
// Block = 4 waves. Each wave processes 16-row strips independently.
// LDS holds Uw pre-packed as MFMA B-fragments: Bs[(cg*4+ks)*64 + lane], bf16x8.
// Per strip per lane: 8 global dwordx4 A-loads, 40 L1-hit vx2 loads (folded
// into acc init), 32 ds_read_b128 B-frags, 32 MFMAs, 32 dword stores.
__global__ __launch_bounds__(256) void edge_kernel(
    const float* __restrict__ e, const float* __restrict__ Uw,
    const float* __restrict__ vx2, float* __restrict__ out) {
  __shared__ alignas(16) bf16x8 Bs[8 * 4 * 64];  // 32 KB

  const int tid = threadIdx.x;

  // ---- stage B fragments once: entry idx = (cg*4+ks)*64 + lane
  // lane needs B[k=ks*32+kg*8+j][n=cg*16+ln] = Uw[cg*16+ln][ks*32+kg*8+j]
#pragma unroll
  for (int k = 0; k < 8; ++k) {
    const int idx  = tid + k * 256;
    const int ll   = idx & 63;
    const int ksi  = (idx >> 6) & 3;
    const int cgi  = idx >> 8;
    const int o    = cgi * 16 + (ll & 15);
    const int kq   = ll >> 4;
    const float4* p = (const float4*)(Uw + (size_t)o * 128 + ksi * 32 + kq * 8);
    Bs[idx] = pack8(p[0], p[1]);
  }
  __syncthreads();  // the ONLY barrier

  const int wave = tid >> 6;
  const int lane = tid & 63;
  const int ln   = lane & 15;  // MFMA m/n index
  const int kg   = lane >> 4;  // MFMA k-quad

  const int gw = blockIdx.x * 4 + wave;   // global wave id
  const int nw = gridDim.x * 4;
  const int nStrips = (8 * 256 * 256) / 16;  // 32768

  for (int s = gw; s < nStrips; s += nw) {
    const size_t rowBase = (size_t)s * 16;  // 16 rows, same (b,i), j = j0..j0+15
    const int bi = (int)(rowBase >> 8);     // b*256 + i
    const int b_ = (int)(rowBase >> 16);    // b
    const int j0 = (int)(rowBase & 255);
    const int jr = b_ * 256 + j0;           // vx2 row base for j

    // ---- A loads: lane's row = rowBase+ln, cols kg*8 + ks*32 + [0..7]
    const float* arow = e + (rowBase + ln) * 128 + kg * 8;
    float4 a0[4], a1[4];
#pragma unroll
    for (int ks = 0; ks < 4; ++ks) {
      a0[ks] = *(const float4*)(arow + ks * 32);
      a1[ks] = *(const float4*)(arow + ks * 32 + 4);
    }

    // ---- accumulator init = vxi[o] + vxj[row][o]  (epilogue fold)
    // C/D layout: col = ln, row = kg*4 + reg
    f32x4 acc[8];
#pragma unroll
    for (int cg = 0; cg < 8; ++cg) {
      const int o = cg * 16 + ln;
      const float vxi = vx2[(size_t)bi * 128 + o];
      const float* vj = vx2 + (size_t)(jr + kg * 4) * 128 + o;
#pragma unroll
      for (int reg = 0; reg < 4; ++reg)
        acc[cg][reg] = vxi + vj[reg * 128];
    }

    // ---- convert A to bf16 fragments
    bf16x8 af[4];
#pragma unroll
    for (int ks = 0; ks < 4; ++ks) af[ks] = pack8(a0[ks], a1[ks]);

    // ---- MFMA: 8 col-groups x 4 k-steps
#pragma unroll
    for (int cg = 0; cg < 8; ++cg) {
      const bf16x8* bp = &Bs[cg * 4 * 64 + lane];
      f32x4 a = acc[cg];
#pragma unroll
      for (int ks = 0; ks < 4; ++ks)
        a = __builtin_amdgcn_mfma_f32_16x16x32_bf16(af[ks], bp[ks * 64], a, 0, 0, 0);
      acc[cg] = a;
    }

    // ---- pure-store epilogue
    float* orow = out + (rowBase + kg * 4) * 128 + ln;
#pragma unroll
    for (int cg = 0; cg < 8; ++cg) {
#pragma unroll
      for (int reg = 0; reg < 4; ++reg)
        orow[reg * 128 + cg * 16] = acc[cg][reg];
    }
  }
}

extern "C" void kernel_launch(void* const* d_in, const int* in_sizes, int n_in,
                              void* d_out, int out_size, void* d_ws, size_t ws_size,
                              hipStream_t stream) {
  // setup_inputs order: x, e, U_w, U_b, V_w, V_b (all fp32)
  const float* x  = (const float*)d_in[0];
  const float* e  = (const float*)d_in[1];
  const float* Uw = (const float*)d_in[2];
  const float* Ub = (const float*)d_in[3];
  const float* Vw = (const float*)d_in[4];
  const float* Vb = (const float*)d_in[5];
  float* out = (float*)d_out;
  float* vx2 = (float*)d_ws;  // 2048*128*4 = 1 MB scratch

  vx_kernel<<<256, 256, 0, stream>>>(x, Vw, Vb, Ub, vx2);
  edge_kernel<<<2048, 256, 0, stream>>>(e, Uw, vx2, out);
}